// Round 5
// baseline (4405.039 us; speedup 1.0000x reference)
//
#include <hip/hip_runtime.h>
#include <hip/hip_bf16.h>
#include <math.h>

// Problem constants (GRUAttnDecoder): B=16, ENC=512, T=64, DIM=768, VOCAB=21128
#define Bdim 16
#define ENC 512
#define Tn 64
#define DIM 768
#define VOCAB 21128
#define SCALEF 0.03608439182435161f  // 1/sqrt(768)
#define NEGF   -1e30f
#define NBLK 256
#define DYN_LDS (100 * 1024)  // 96KB ctx tile + scratch; forces 1 block/CU

__device__ __forceinline__ float wred_sum(float v) {
#pragma unroll
  for (int m = 32; m >= 1; m >>= 1) v += __shfl_xor(v, m, 64);
  return v;
}
__device__ __forceinline__ float sigmf(float x) { return 1.0f / (1.0f + __expf(-x)); }

// coherent (IF-level) access helpers — the only cross-block primitives we use
__device__ __forceinline__ void astore(float* p, float v) {
  __hip_atomic_store(p, v, __ATOMIC_RELAXED, __HIP_MEMORY_SCOPE_AGENT);
}
__device__ __forceinline__ void astoreu(unsigned* p, unsigned v) {
  __hip_atomic_store(p, v, __ATOMIC_RELAXED, __HIP_MEMORY_SCOPE_AGENT);
}
__device__ __forceinline__ void astore2(float* p, float a, float b) {
  float2 v = make_float2(a, b);
  __hip_atomic_store((unsigned long long*)p, *(unsigned long long*)&v,
                     __ATOMIC_RELAXED, __HIP_MEMORY_SCOPE_AGENT);
}
__device__ __forceinline__ float aloadf(const float* p) {
  return __hip_atomic_load(const_cast<float*>(p), __ATOMIC_RELAXED, __HIP_MEMORY_SCOPE_AGENT);
}
__device__ __forceinline__ unsigned afadd(unsigned* p) {
  return __hip_atomic_fetch_add(p, 1u, __ATOMIC_RELAXED, __HIP_MEMORY_SCOPE_AGENT);
}
__device__ __forceinline__ unsigned aloadu(const unsigned* p) {
  return __hip_atomic_load(const_cast<unsigned*>(p), __ATOMIC_RELAXED, __HIP_MEMORY_SCOPE_AGENT);
}

// ---- RMW-free flag barriers (monotone epochs, zeroed once per launch) ----
// Arrival = ONE agent store into the block's own dword of a per-XCD 128B flag
// line (no same-line RMW serialization). Leader (slot 0) polls all 32 flags
// with a single coalesced 32-lane agent load until all >= ep, then stores
// rf[xcd] = ep. All blocks poll the 8-dword root line coalesced (lanes 0..7).
// Monotone >= comparisons make one shared flag array safe across phases.
// Data visibility: __syncthreads drains each wave's vmcnt (compiler-enforced),
// so flag >= ep implies that block's agent stores are at IF.
__device__ __forceinline__ void lbarf(unsigned* fl, int xcd, int slot, unsigned ep) {
  __syncthreads();
  if (threadIdx.x < 64) {
    if (threadIdx.x == 0) {
      asm volatile("s_waitcnt vmcnt(0)" ::: "memory");
      astoreu(&fl[xcd * 32 + slot], ep);
    }
    for (;;) {
      unsigned v = (threadIdx.x < 32) ? aloadu(&fl[xcd * 32 + threadIdx.x]) : ep;
      if (!__any(v < ep)) break;
      __builtin_amdgcn_s_sleep(1);
    }
  }
  __syncthreads();
}
__device__ __forceinline__ void gbarf(unsigned* fl, unsigned* rf, int xcd, int slot,
                                      unsigned ep) {
  __syncthreads();
  if (threadIdx.x < 64) {
    if (threadIdx.x == 0) {
      asm volatile("s_waitcnt vmcnt(0)" ::: "memory");
      astoreu(&fl[xcd * 32 + slot], ep);
    }
    if (slot == 0) {
      for (;;) {
        unsigned v = (threadIdx.x < 32) ? aloadu(&fl[xcd * 32 + threadIdx.x]) : ep;
        if (!__any(v < ep)) break;
        __builtin_amdgcn_s_sleep(1);
      }
      if (threadIdx.x == 0) astoreu(&rf[xcd], ep);
    }
    for (;;) {
      unsigned r = (threadIdx.x < 8) ? aloadu(&rf[threadIdx.x]) : ep;
      if (!__any(r < ep)) break;
      __builtin_amdgcn_s_sleep(1);
    }
  }
  __syncthreads();
}

// bf16 pack helpers (manual RNE)
__device__ __forceinline__ unsigned int f2bf(float f) {
  unsigned int u = __float_as_uint(f);
  u += 0x7fffu + ((u >> 16) & 1u);
  return u >> 16;
}
__device__ __forceinline__ float bflo(unsigned int p) { return __uint_as_float(p << 16); }
__device__ __forceinline__ float bfhi(unsigned int p) { return __uint_as_float(p & 0xffff0000u); }

// ---------------- init ----------------
__global__ void k_zero_coh(unsigned long long* __restrict__ p, int n64) {
  int i = blockIdx.x * blockDim.x + threadIdx.x;
  int st = gridDim.x * blockDim.x;
  for (; i < n64; i += st)
    __hip_atomic_store(&p[i], 0ULL, __ATOMIC_RELAXED, __HIP_MEMORY_SCOPE_AGENT);
}

__global__ void k_h0(const float* __restrict__ init_h, float* __restrict__ h_all) {
  int i = blockIdx.x * blockDim.x + threadIdx.x;
  if (i < Bdim * DIM) h_all[i] = init_h[i % DIM];
}

// ---- precompute emb-part of gate preactivations + bias for all (t,b) ----
__global__ void __launch_bounds__(256, 2) k_pre(
    const int* __restrict__ din, const float* __restrict__ emb,
    const float* __restrict__ Wr, const float* __restrict__ br,
    const float* __restrict__ Wu, const float* __restrict__ bu,
    const float* __restrict__ Wc, const float* __restrict__ bc,
    float* __restrict__ P_ru, float* __restrict__ P_c) {
  const int nb = blockIdx.x, tbc = blockIdx.y;
  const int n = nb * 256 + threadIdx.x;
  const float* wrow;
  float bias;
  if (n < 768)       { wrow = Wr + n * 2304 + 768;          bias = br[n]; }
  else if (n < 1536) { wrow = Wu + (n - 768) * 2304 + 768;  bias = bu[n - 768]; }
  else               { wrow = Wc + (n - 1536) * 2304 + 768; bias = bc[n - 1536]; }
  int id[16];
#pragma unroll
  for (int i = 0; i < 16; ++i) {
    int row = tbc * 16 + i;  // row = t*16 + b
    id[i] = din[(row & 15) * Tn + (row >> 4)];
  }
  float acc[16];
#pragma unroll
  for (int i = 0; i < 16; ++i) acc[i] = bias;
  for (int k = 0; k < DIM; k += 4) {
    float4 w = *(const float4*)(wrow + k);
#pragma unroll
    for (int i = 0; i < 16; ++i) {
      float4 x = *(const float4*)(emb + (size_t)id[i] * DIM + k);
      acc[i] = fmaf(w.x, x.x, fmaf(w.y, x.y, fmaf(w.z, x.z, fmaf(w.w, x.w, acc[i]))));
    }
  }
#pragma unroll
  for (int i = 0; i < 16; ++i) {
    int row = tbc * 16 + i;
    if (n < 1536) P_ru[(size_t)row * 1536 + n] = acc[i];
    else          P_c[(size_t)row * 768 + (n - 1536)] = acc[i];
  }
}

// ---- persistent sequential kernel — ctx lives in LDS for all 64 steps ----
// block identity: physical (xcd, slot<32). attention batch bA = 2*xcd+(slot&1),
// chunk = slot>>1 (32 enc positions, staged in LDS). gid = xcd*32+slot owns
// r rows gid*3.., u rows = c rows = gid*3.. (u never leaves registers).
// Per t: A1 (scores from LDS -> e_lds) | A2a (esum + 768-dim partial from LDS
// -> pbuf/psum astore) | lbarf | A2b (sum 16 partials -> normalized attnc slice
// astore) | gbarf | B (r astore, u regs) | gbarf | C (c + h update astore) | gbarf.
__global__ void __launch_bounds__(512, 1) k_seq(
    const float* __restrict__ ctx, const float* __restrict__ mask,
    const float* __restrict__ Wr, const float* __restrict__ Wu,
    const float* __restrict__ Wc,
    const float* __restrict__ P_ru, const float* __restrict__ P_c,
    float* __restrict__ h_all, float* __restrict__ attnc,
    float* __restrict__ r_coh, float* __restrict__ pbuf,
    float* __restrict__ psum,
    unsigned* __restrict__ slotctr, unsigned* __restrict__ fl,
    unsigned* __restrict__ rf) {
  extern __shared__ float dynpad[];
  float* ctx_lds = dynpad;              // [32][768] = 24576 floats (96 KB)
  float* e_lds   = dynpad + 24576;      // [32]
  float* pred    = dynpad + 24576 + 32; // [48][17] padded = 816
  float* psh     = dynpad + 24576 + 32 + 816;  // [16]
  __shared__ int slot_sh;
  const int tid = threadIdx.x;
  const int lane = tid & 63;
  const int wv = tid >> 6;  // 0..7
  int xcd;
  asm volatile("s_getreg_b32 %0, hwreg(HW_REG_XCC_ID)" : "=s"(xcd));
  xcd &= 7;
  if (tid == 0) slot_sh = (int)afadd(&slotctr[xcd * 16]);
  __syncthreads();
  const int slot = slot_sh;            // 0..31 (1 block/CU guaranteed by LDS)
  const int gid = xcd * 32 + slot;     // 0..255 unique
  const int bA = 2 * xcd + (slot & 1); // attention batch
  const int chunk = slot >> 1;         // 0..15 (32 positions)
  const int dsl = chunk * 48;          // A2b dim-slice base
  const int rg0 = gid * 3;             // r rows 0..767
  const int cg0 = gid * 3;             // u & c rows 0..767
  const int b0 = 2 * wv;               // this wave's two batches (phases B/C)

  // ---- stage this block's ctx chunk (32 rows x 768) into LDS, ONCE ----
  {
    const float* chunkbase = ctx + ((size_t)(bA * ENC + chunk * 32)) * DIM;
#pragma unroll
    for (int k = 0; k < 12; ++k) {
      const int f = k * 2048 + tid * 4;
      *(float4*)(ctx_lds + f) = *(const float4*)(chunkbase + f);
    }
  }

  // ---- stage 9 W rows (3 Wr, 3 Wu, 3 Wc) into per-lane VGPRs (bf16 packed)
  unsigned int wreg[9][12];
#pragma unroll
  for (int i = 0; i < 9; ++i) {
    const float* src = (i < 3) ? (Wr + (size_t)(rg0 + i) * 2304)
                     : (i < 6) ? (Wu + (size_t)(cg0 + i - 3) * 2304)
                               : (Wc + (size_t)(cg0 + i - 6) * 2304);
#pragma unroll
    for (int j = 0; j < 6; ++j) {
      int xcol = 4 * lane + 256 * j;
      int scol = (j < 3) ? xcol : (1536 + xcol - 768);
      float4 v = *(const float4*)(src + scol);
      wreg[i][2 * j]     = (f2bf(v.x)) | (f2bf(v.y) << 16);
      wreg[i][2 * j + 1] = (f2bf(v.z)) | (f2bf(v.w) << 16);
    }
  }
  // attention mask-add for this wave's 4 positions
  float madd[4];
#pragma unroll
  for (int i = 0; i < 4; ++i)
    madd[i] = (1.0f - mask[bA * ENC + chunk * 32 + 4 * wv + i]) * NEGF;

  __syncthreads();  // ctx_lds ready for all waves

  unsigned ep = 1;  // monotone barrier epoch (4 per t-step)
  for (int t = 0; t < Tn; ++t) {
    // ===== A1: scores for this chunk's 32 rows (4 per wave), from LDS ======
    {
      const float* hrow = h_all + (size_t)(t * Bdim + bA) * DIM;
      float hreg[12];
#pragma unroll
      for (int j = 0; j < 12; ++j) hreg[j] = hrow[lane + 64 * j];
#pragma unroll
      for (int i = 0; i < 4; ++i) {
        const int rr = 4 * wv + i;
        const float* crow = ctx_lds + rr * 768;
        float dot = 0.f;
#pragma unroll
        for (int j = 0; j < 12; ++j) dot = fmaf(crow[lane + 64 * j], hreg[j], dot);
        dot = wred_sum(dot);
        if (lane == 0) e_lds[rr] = __expf(fmaf(dot, SCALEF, madd[i]));
      }
    }
    __syncthreads();  // e_lds ready

    // ===== A2a: own esum + 768-dim weighted partial over own 32 LDS rows ===
    if (wv == 0) {
      float ev = (lane < 32) ? e_lds[lane] : 0.f;
      float es = wred_sum(ev);
      if (lane == 0) astore(&psum[bA * 16 + chunk], es);
    }
    if (tid < 384) {
      const int d0 = 2 * tid;
      float a0 = 0.f, a1 = 0.f;
#pragma unroll 8
      for (int r = 0; r < 32; ++r) {
        const float e = e_lds[r];
        const float2 c2 = *(const float2*)(ctx_lds + r * 768 + d0);
        a0 = fmaf(e, c2.x, a0);
        a1 = fmaf(e, c2.y, a1);
      }
      astore2(&pbuf[(size_t)(bA * 16 + chunk) * 768 + d0], a0, a1);
    }
    lbarf(fl, xcd, slot, ep++);  // partials for this XCD's 2 batches done

    // ===== A2b: sum 16 partials (48-dim slice) + den -> normalized attnc ===
    {
      // coalesced agent reads: round 1 = offsets 0..31 x 16 chunks
      const int p1 = tid >> 5, o1 = tid & 31;
      float v1 = aloadf(&pbuf[(size_t)(bA * 16 + p1) * 768 + dsl + o1]);
      float v2 = 0.f;
      int p2 = 0, o2 = 0;
      if (tid < 256) {  // round 2 = offsets 32..47 x 16 chunks
        p2 = tid >> 4; o2 = 32 + (tid & 15);
        v2 = aloadf(&pbuf[(size_t)(bA * 16 + p2) * 768 + dsl + o2]);
      }
      if (tid < 16) psh[tid] = aloadf(&psum[bA * 16 + tid]);
      pred[o1 * 17 + p1] = v1;
      if (tid < 256) pred[o2 * 17 + p2] = v2;
      __syncthreads();
      if (tid < 48) {
        float s = 0.f, den = 0.f;
#pragma unroll
        for (int p = 0; p < 16; ++p) { s += pred[tid * 17 + p]; den += psh[p]; }
        astore(&attnc[(size_t)(t * Bdim + bA) * DIM + dsl + tid], s / den);
      }
    }
    gbarf(fl, rf, xcd, slot, ep++);

    // ============ B: r rows (astore) + u rows (stay in registers) ===========
    float4 xv[2][6];
#pragma unroll
    for (int bb = 0; bb < 2; ++bb) {
      const int b = b0 + bb;
      const float* ab = attnc + (size_t)(t * Bdim + b) * DIM;  // pre-normalized
      const float* hb = h_all + (size_t)(t * Bdim + b) * DIM;
#pragma unroll
      for (int j = 0; j < 3; ++j)
        xv[bb][j] = *(const float4*)(ab + 4 * lane + 256 * j);
#pragma unroll
      for (int j = 0; j < 3; ++j)
        xv[bb][3 + j] = *(const float4*)(hb + 4 * lane + 256 * j);
    }
    float u_reg[3];
#pragma unroll
    for (int i = 0; i < 3; ++i) {  // r rows rg0..rg0+2
      float d0 = 0.f, d1 = 0.f;
#pragma unroll
      for (int j = 0; j < 6; ++j) {
        const unsigned int p0 = wreg[i][2 * j], p1 = wreg[i][2 * j + 1];
        const float w0 = bflo(p0), w1 = bfhi(p0), w2 = bflo(p1), w3 = bfhi(p1);
        d0 = fmaf(w0, xv[0][j].x, fmaf(w1, xv[0][j].y, fmaf(w2, xv[0][j].z, fmaf(w3, xv[0][j].w, d0))));
        d1 = fmaf(w0, xv[1][j].x, fmaf(w1, xv[1][j].y, fmaf(w2, xv[1][j].z, fmaf(w3, xv[1][j].w, d1))));
      }
      d0 = wred_sum(d0);
      d1 = wred_sum(d1);
      if (lane < 2) {
        const int b = b0 + lane;
        const int row = rg0 + i;
        const float s = sigmf(P_ru[(size_t)(t * Bdim + b) * 1536 + row] + (lane ? d1 : d0));
        astore(&r_coh[(size_t)(t * Bdim + b) * DIM + row], s);
      }
    }
#pragma unroll
    for (int i = 0; i < 3; ++i) {  // u rows cg0..cg0+2 (register-resident)
      float d0 = 0.f, d1 = 0.f;
#pragma unroll
      for (int j = 0; j < 6; ++j) {
        const unsigned int p0 = wreg[3 + i][2 * j], p1 = wreg[3 + i][2 * j + 1];
        const float w0 = bflo(p0), w1 = bfhi(p0), w2 = bflo(p1), w3 = bfhi(p1);
        d0 = fmaf(w0, xv[0][j].x, fmaf(w1, xv[0][j].y, fmaf(w2, xv[0][j].z, fmaf(w3, xv[0][j].w, d0))));
        d1 = fmaf(w0, xv[1][j].x, fmaf(w1, xv[1][j].y, fmaf(w2, xv[1][j].z, fmaf(w3, xv[1][j].w, d1))));
      }
      d0 = wred_sum(d0);
      d1 = wred_sum(d1);
      if (lane < 2) {
        const int b = b0 + lane;
        u_reg[i] = sigmf(P_ru[(size_t)(t * Bdim + b) * 1536 + 768 + cg0 + i] + (lane ? d1 : d0));
      }
    }
    gbarf(fl, rf, xcd, slot, ep++);

    // ============ C: c gate + h update (u from registers) ===================
#pragma unroll
    for (int bb = 0; bb < 2; ++bb) {
      const int b = b0 + bb;
      const float* rb = r_coh + (size_t)(t * Bdim + b) * DIM;
#pragma unroll
      for (int j = 0; j < 3; ++j) {
        float4 rv = *(const float4*)(rb + 4 * lane + 256 * j);  // fresh t-line
        xv[bb][3 + j].x *= rv.x; xv[bb][3 + j].y *= rv.y;
        xv[bb][3 + j].z *= rv.z; xv[bb][3 + j].w *= rv.w;
      }
    }
#pragma unroll
    for (int i = 0; i < 3; ++i) {
      float d0 = 0.f, d1 = 0.f;
#pragma unroll
      for (int j = 0; j < 6; ++j) {
        const unsigned int p0 = wreg[6 + i][2 * j], p1 = wreg[6 + i][2 * j + 1];
        const float w0 = bflo(p0), w1 = bfhi(p0), w2 = bflo(p1), w3 = bfhi(p1);
        d0 = fmaf(w0, xv[0][j].x, fmaf(w1, xv[0][j].y, fmaf(w2, xv[0][j].z, fmaf(w3, xv[0][j].w, d0))));
        d1 = fmaf(w0, xv[1][j].x, fmaf(w1, xv[1][j].y, fmaf(w2, xv[1][j].z, fmaf(w3, xv[1][j].w, d1))));
      }
      d0 = wred_sum(d0);
      d1 = wred_sum(d1);
      if (lane < 2) {
        const int b = b0 + lane;
        const int row = cg0 + i;
        const float c = tanhf(P_c[(size_t)(t * Bdim + b) * DIM + row] + (lane ? d1 : d0));
        const float hp = h_all[(size_t)(t * Bdim + b) * DIM + row];
        astore(&h_all[(size_t)((t + 1) * Bdim + b) * DIM + row], hp + u_reg[i] * (c - hp));
      }
    }
    gbarf(fl, rf, xcd, slot, ep++);
  }
}

// ---- deferred: out_all & copyq for all 1024 rows ----
__global__ void __launch_bounds__(256, 2) k_out(
    const float* __restrict__ Wo, const float* __restrict__ bo,
    const float* __restrict__ Wcp, const float* __restrict__ bcp,
    const float* __restrict__ h_all, float* __restrict__ out_all,
    float* __restrict__ copyq) {
  const int nb = blockIdx.x, tbc = blockIdx.y;
  const int n = nb * 256 + threadIdx.x;  // 0..1535
  const float* wrow;
  float bias;
  if (n < 768) { wrow = Wo + (size_t)n * 768;          bias = bo[n]; }
  else         { wrow = Wcp + (size_t)(n - 768) * 768; bias = bcp[n - 768]; }
  const float* hbase = h_all + (size_t)(tbc * 16 + 16) * DIM;  // h_new = slot t+1
  float acc[16];
#pragma unroll
  for (int i = 0; i < 16; ++i) acc[i] = bias;
  for (int k = 0; k < DIM; k += 4) {
    float4 w = *(const float4*)(wrow + k);
#pragma unroll
    for (int i = 0; i < 16; ++i) {
      float4 x = *(const float4*)(hbase + i * DIM + k);
      acc[i] = fmaf(w.x, x.x, fmaf(w.y, x.y, fmaf(w.z, x.z, fmaf(w.w, x.w, acc[i]))));
    }
  }
#pragma unroll
  for (int i = 0; i < 16; ++i) {
    int row = tbc * 16 + i;
    if (n < 768) out_all[(size_t)row * 768 + n] = acc[i];
    else         copyq[(size_t)row * 768 + (n - 768)] = acc[i];
  }
}

// ---- deferred: copy softmax num/den per (t,b) ----
__global__ void __launch_bounds__(512, 2) k_copy(
    const int* __restrict__ ids, const int* __restrict__ dtg,
    const float* __restrict__ ctx, const float* __restrict__ mask,
    const float* __restrict__ copyq,
    float* __restrict__ cnum, float* __restrict__ cden) {
  const int sc = blockIdx.x, b = blockIdx.y;
  const int lane = threadIdx.x & 63;
  const int seg = __builtin_amdgcn_readfirstlane(threadIdx.x >> 6);
  const int s = sc * 64 + lane;
  __shared__ float part[8][64];
  float creg[96];
  const float* crow = ctx + ((size_t)(b * ENC + s)) * DIM + seg * 96;
#pragma unroll
  for (int kk = 0; kk < 96; kk += 4) {
    float4 v = *(const float4*)(crow + kk);
    creg[kk] = v.x; creg[kk + 1] = v.y; creg[kk + 2] = v.z; creg[kk + 3] = v.w;
  }
  const float madd = (1.0f - mask[b * ENC + s]) * NEGF;
  const int myid = ids[b * ENC + s];
  for (int t = 0; t < Tn; ++t) {
    const int row = t * Bdim + b;
    const float* q = copyq + (size_t)row * 768 + seg * 96;
    float dot = 0.f;
#pragma unroll
    for (int kk = 0; kk < 96; kk += 4) {
      float4 qv = *(const float4*)(q + kk);
      dot = fmaf(qv.x, creg[kk], fmaf(qv.y, creg[kk + 1],
            fmaf(qv.z, creg[kk + 2], fmaf(qv.w, creg[kk + 3], dot))));
    }
    part[seg][lane] = dot;
    __syncthreads();
    if (threadIdx.x < 64) {
      float logit = madd;
#pragma unroll
      for (int w = 0; w < 8; ++w) logit += part[w][lane];
      float e = __expf(logit);
      int tgt = dtg[b * Tn + t];
      float ne = (myid == tgt) ? e : 0.f;
      float dsum = wred_sum(e);
      float nsum = wred_sum(ne);
      if (lane == 0) {
        atomicAdd(&cden[row], dsum);
        if (nsum != 0.f) atomicAdd(&cnum[row], nsum);
      }
    }
    __syncthreads();
  }
}

// ---- deferred: vocab exp-sum per row. grid (83, 16) x 256, 64 rows/block ----
__global__ void __launch_bounds__(256, 1) k_vocab(
    const float* __restrict__ emb, const float* __restrict__ out_all,
    float* __restrict__ S) {
  const int vc = blockIdx.x, tbc = blockIdx.y;
  const int tb0 = tbc * 64;
  const int v = vc * 256 + threadIdx.x;
  const bool valid = v < VOCAB;
  const int vv = valid ? v : 0;
  float acc[64];
#pragma unroll
  for (int i = 0; i < 64; ++i) acc[i] = 0.f;
  const float* erow = emb + (size_t)vv * DIM;
  const float* ob = out_all + (size_t)tb0 * DIM;
  for (int k = 0; k < DIM; k += 4) {
    float4 w = *(const float4*)(erow + k);
#pragma unroll
    for (int i = 0; i < 64; ++i) {
      float4 a = *(const float4*)(ob + (size_t)i * DIM + k);
      acc[i] = fmaf(w.x, a.x, fmaf(w.y, a.y, fmaf(w.z, a.z, fmaf(w.w, a.w, acc[i]))));
    }
  }
  __shared__ float rowsum[64];
  if (threadIdx.x < 64) rowsum[threadIdx.x] = 0.f;
  __syncthreads();
  const int lane = threadIdx.x & 63;
#pragma unroll
  for (int i = 0; i < 64; ++i) {
    float e = valid ? __expf(acc[i]) : 0.f;
    float r = wred_sum(e);
    if (lane == 0) atomicAdd(&rowsum[i], r);
  }
  __syncthreads();
  if (threadIdx.x < 64) atomicAdd(&S[tb0 + threadIdx.x], rowsum[threadIdx.x]);
}

// ---- deferred: per-row target prob + loss accumulation ----
__global__ void k_tgt(
    const int* __restrict__ dtg, const float* __restrict__ out_all,
    const float* __restrict__ emb, const float* __restrict__ Wm,
    const float* __restrict__ bm, const float* __restrict__ h_all,
    const float* __restrict__ S, const float* __restrict__ cnum,
    const float* __restrict__ cden, float* __restrict__ loss) {
  const int lane = threadIdx.x & 63;
  const int w = __builtin_amdgcn_readfirstlane(threadIdx.x >> 6);
  for (int rr = 0; rr < 16; ++rr) {
    const int row = (blockIdx.x * 4 + w) * 16 + rr;
    const int t = row >> 4, b = row & 15;
    const int tgt = dtg[b * Tn + t];
    const float* orow = out_all + (size_t)row * DIM + lane * 12;
    const float* erow = emb + (size_t)tgt * DIM + lane * 12;
    const float* hrow = h_all + (size_t)(row + 16) * DIM + lane * 12;
    const float* wm = Wm + lane * 12;
    float lt = 0.f, md = 0.f;
#pragma unroll
    for (int k = 0; k < 12; k += 4) {
      float4 o = *(const float4*)(orow + k);
      float4 e = *(const float4*)(erow + k);
      float4 h = *(const float4*)(hrow + k);
      float4 m = *(const float4*)(wm + k);
      lt = fmaf(o.x, e.x, fmaf(o.y, e.y, fmaf(o.z, e.z, fmaf(o.w, e.w, lt))));
      md = fmaf(m.x, h.x, fmaf(m.y, h.y, fmaf(m.z, h.z, fmaf(m.w, h.w, md))));
    }
    lt = wred_sum(lt);
    md = wred_sum(md);
    if (lane == 0 && tgt != 0) {
      float mode = sigmf(md + bm[0]);
      float pv = __expf(lt) / S[row] * mode;
      float den = cden[row];
      float pc = (den > 0.f) ? (cnum[row] / den) : 0.f;
      float p = pv + (1.0f - mode) * pc;
      atomicAdd(&loss[0], -logf(p + 1e-6f));
      atomicAdd(&loss[1], 1.0f);
    }
  }
}

__global__ void k_write(const float* __restrict__ loss, float* __restrict__ out) {
  if (threadIdx.x < Bdim) out[threadIdx.x] = loss[0] / loss[1];
}

extern "C" void kernel_launch(void* const* d_in, const int* in_sizes, int n_in,
                              void* d_out, int out_size, void* d_ws, size_t ws_size,
                              hipStream_t stream) {
  (void)in_sizes; (void)n_in; (void)out_size; (void)ws_size;
  const int*   input_ids = (const int*)d_in[0];
  const float* ctx       = (const float*)d_in[1];
  const float* cmask     = (const float*)d_in[2];
  const int*   din       = (const int*)d_in[3];
  const int*   dtg       = (const int*)d_in[4];
  const float* embW      = (const float*)d_in[7];
  const float* Wr = (const float*)d_in[8];  const float* br  = (const float*)d_in[9];
  const float* Wu = (const float*)d_in[10]; const float* bu  = (const float*)d_in[11];
  const float* Wc = (const float*)d_in[12]; const float* bc  = (const float*)d_in[13];
  const float* Wo = (const float*)d_in[14]; const float* bo  = (const float*)d_in[15];
  const float* Wcp= (const float*)d_in[16]; const float* bcp = (const float*)d_in[17];
  const float* Wm = (const float*)d_in[18]; const float* bm  = (const float*)d_in[19];
  const float* ih = (const float*)d_in[20];

  float* ws      = (float*)d_ws;
  float* P_ru    = ws;                          // 1024*1536
  float* P_c     = P_ru + 1024 * 1536;          // 1024*768
  float* h_all   = P_c + 1024 * 768;            // 65*16*768
  float* out_all = h_all + 65 * 16 * 768;       // 1024*768
  float* copyq   = out_all + 1024 * 768;        // 1024*768
  float* attnc   = copyq + 1024 * 768;          // 64*16*768 (normalized attn)
  float* r_coh   = attnc + 64 * 16 * 768;       // 64*16*768 (per-t fresh lines)
  float* pbuf    = r_coh + 64 * 16 * 768;       // 16*16*768 (agent-only access)
  float* psum    = pbuf + 16 * 16 * 768;        // 256      (agent-only access)
  // ---- coherently-zeroed region ----
  float* S       = psum + 256;                  // 1024
  float* cnum    = S + 1024;                    // 1024
  float* cden    = cnum + 1024;                 // 1024
  float* loss    = cden + 1024;                 // 2 (+30 pad -> 128B alignment)
  unsigned* slotctr = (unsigned*)(loss + 32);   // 8*16 = 128
  unsigned* fl      = slotctr + 128;            // 8 XCDs * 32 (one 128B line each)
  unsigned* rf      = fl + 8 * 32;              // 8 (+24 pad)
  const int nzero64 = (3 * 1024 + 32 + 128 + 8 * 32 + 32) / 2;

  hipFuncSetAttribute((const void*)k_seq,
                      hipFuncAttributeMaxDynamicSharedMemorySize, DYN_LDS);

  k_zero_coh<<<64, 1024, 0, stream>>>((unsigned long long*)S, nzero64);
  k_h0<<<12, 1024, 0, stream>>>(ih, h_all);
  k_pre<<<dim3(9, 64), 256, 0, stream>>>(din, embW, Wr, br, Wu, bu, Wc, bc, P_ru, P_c);

  k_seq<<<NBLK, 512, DYN_LDS, stream>>>(ctx, cmask, Wr, Wu, Wc, P_ru, P_c,
                                        h_all, attnc, r_coh, pbuf, psum,
                                        slotctr, fl, rf);

  k_out<<<dim3(6, 64), 256, 0, stream>>>(Wo, bo, Wcp, bcp, h_all, out_all, copyq);
  k_copy<<<dim3(8, 16), 512, 0, stream>>>(input_ids, dtg, ctx, cmask, copyq, cnum, cden);
  k_vocab<<<dim3(83, 16), 256, 0, stream>>>(embW, out_all, S);
  k_tgt<<<16, 256, 0, stream>>>(dtg, out_all, embW, Wm, bm, h_all, S, cnum, cden, loss);
  k_write<<<1, 64, 0, stream>>>(loss, (float*)d_out);
}

// Round 6
// 4140.633 us; speedup vs baseline: 1.0639x; 1.0639x over previous
//
#include <hip/hip_runtime.h>
#include <hip/hip_bf16.h>
#include <math.h>

// Problem constants (GRUAttnDecoder): B=16, ENC=512, T=64, DIM=768, VOCAB=21128
#define Bdim 16
#define ENC 512
#define Tn 64
#define DIM 768
#define VOCAB 21128
#define SCALEF 0.03608439182435161f  // 1/sqrt(768)
#define NEGF   -1e30f
#define NBLK 256
#define DYN_LDS (100 * 1024)  // 96KB ctx tile + scratch; forces 1 block/CU

__device__ __forceinline__ float wred_sum(float v) {
#pragma unroll
  for (int m = 32; m >= 1; m >>= 1) v += __shfl_xor(v, m, 64);
  return v;
}
__device__ __forceinline__ float sigmf(float x) { return 1.0f / (1.0f + __expf(-x)); }

// ---- agent (IF-coherent) primitives (proven) ----
__device__ __forceinline__ void astore(float* p, float v) {
  __hip_atomic_store(p, v, __ATOMIC_RELAXED, __HIP_MEMORY_SCOPE_AGENT);
}
__device__ __forceinline__ unsigned afadd(unsigned* p) {
  return __hip_atomic_fetch_add(p, 1u, __ATOMIC_RELAXED, __HIP_MEMORY_SCOPE_AGENT);
}
__device__ __forceinline__ unsigned aloadu(const unsigned* p) {
  return __hip_atomic_load(const_cast<unsigned*>(p), __ATOMIC_RELAXED, __HIP_MEMORY_SCOPE_AGENT);
}

// ---- XCD-L2-local data path (producers+consumers on the SAME XCD only) ----
// workgroup-scope store -> write-through to the XCD's L2; sc0 load -> bypass
// CU L1, served by the XCD's L2 (R2/R5-validated pattern). Cross-launch dirty
// lines are harmless: every line is overwritten before it is read each step.
__device__ __forceinline__ void wstore(float* p, float v) {
  __hip_atomic_store(p, v, __ATOMIC_RELAXED, __HIP_MEMORY_SCOPE_WORKGROUP);
}
__device__ __forceinline__ void wstore2(float* p, float a, float b) {
  float2 v = make_float2(a, b);
  __hip_atomic_store((unsigned long long*)p, *(unsigned long long*)&v,
                     __ATOMIC_RELAXED, __HIP_MEMORY_SCOPE_WORKGROUP);
}
__device__ __forceinline__ float l2ldf(const float* p) {
  unsigned u;
  asm volatile("global_load_dword %0, %1, off sc0\n\ts_waitcnt vmcnt(0)"
               : "=&v"(u) : "v"(p) : "memory");
  return __uint_as_float(u);
}
__device__ __forceinline__ float2 l2ldf2(const float* p) {
  unsigned long long u;
  asm volatile("global_load_dwordx2 %0, %1, off sc0\n\ts_waitcnt vmcnt(0)"
               : "=&v"(u) : "v"(p) : "memory");
  return make_float2(__uint_as_float((unsigned)u),
                     __uint_as_float((unsigned)(u >> 32)));
}

// ---- barriers: R4 counter form + multi-wave staggered detect ----
// 2 waves poll the flag concurrently (phase-offset loads); first detector sets
// the LDS 'done' flag; everyone joins at __syncthreads (which also drains each
// wave's vmcnt -> data-visibility chain as in all prior passing versions).
__device__ __forceinline__ void mpoll(const unsigned* p, unsigned tgt,
                                      volatile int* done) {
  const int lane = threadIdx.x & 63;
  const int wv = threadIdx.x >> 6;
  if (lane == 0 && wv < 2) {
    while (*done == 0) {
      if (aloadu(p) >= tgt) *done = 1;
    }
  }
  __syncthreads();
}
__device__ __forceinline__ void gbar(unsigned* leaf, unsigned* root, int idx,
                                     int xcd, volatile int* done) {
  if (threadIdx.x == 0) *done = 0;
  __syncthreads();  // publishes done=0; drains all waves' vmcnt
  if (threadIdx.x == 0) {
    asm volatile("s_waitcnt vmcnt(0)" ::: "memory");
    unsigned prev = afadd(&leaf[(idx * 8 + xcd) * 16]);
    if (((prev + 1u) & 31u) == 0u) afadd(&root[idx * 16]);
  }
  mpoll(&root[idx * 16], 8u, done);
}
__device__ __forceinline__ void lbar(unsigned* lbc, int xcd, unsigned tgt,
                                     volatile int* done) {
  if (threadIdx.x == 0) *done = 0;
  __syncthreads();
  if (threadIdx.x == 0) {
    asm volatile("s_waitcnt vmcnt(0)" ::: "memory");
    afadd(&lbc[xcd * 16]);
  }
  mpoll(&lbc[xcd * 16], tgt, done);
}

// bf16 pack helpers (manual RNE)
__device__ __forceinline__ unsigned int f2bf(float f) {
  unsigned int u = __float_as_uint(f);
  u += 0x7fffu + ((u >> 16) & 1u);
  return u >> 16;
}
__device__ __forceinline__ float bflo(unsigned int p) { return __uint_as_float(p << 16); }
__device__ __forceinline__ float bfhi(unsigned int p) { return __uint_as_float(p & 0xffff0000u); }

// ---------------- init ----------------
__global__ void k_zero_coh(unsigned long long* __restrict__ p, int n64) {
  int i = blockIdx.x * blockDim.x + threadIdx.x;
  int st = gridDim.x * blockDim.x;
  for (; i < n64; i += st)
    __hip_atomic_store(&p[i], 0ULL, __ATOMIC_RELAXED, __HIP_MEMORY_SCOPE_AGENT);
}

__global__ void k_h0(const float* __restrict__ init_h, float* __restrict__ h_all) {
  int i = blockIdx.x * blockDim.x + threadIdx.x;
  if (i < Bdim * DIM) h_all[i] = init_h[i % DIM];
}

// ---- precompute emb-part of gate preactivations + bias for all (t,b) ----
__global__ void __launch_bounds__(256, 2) k_pre(
    const int* __restrict__ din, const float* __restrict__ emb,
    const float* __restrict__ Wr, const float* __restrict__ br,
    const float* __restrict__ Wu, const float* __restrict__ bu,
    const float* __restrict__ Wc, const float* __restrict__ bc,
    float* __restrict__ P_ru, float* __restrict__ P_c) {
  const int nb = blockIdx.x, tbc = blockIdx.y;
  const int n = nb * 256 + threadIdx.x;
  const float* wrow;
  float bias;
  if (n < 768)       { wrow = Wr + n * 2304 + 768;          bias = br[n]; }
  else if (n < 1536) { wrow = Wu + (n - 768) * 2304 + 768;  bias = bu[n - 768]; }
  else               { wrow = Wc + (n - 1536) * 2304 + 768; bias = bc[n - 1536]; }
  int id[16];
#pragma unroll
  for (int i = 0; i < 16; ++i) {
    int row = tbc * 16 + i;  // row = t*16 + b
    id[i] = din[(row & 15) * Tn + (row >> 4)];
  }
  float acc[16];
#pragma unroll
  for (int i = 0; i < 16; ++i) acc[i] = bias;
  for (int k = 0; k < DIM; k += 4) {
    float4 w = *(const float4*)(wrow + k);
#pragma unroll
    for (int i = 0; i < 16; ++i) {
      float4 x = *(const float4*)(emb + (size_t)id[i] * DIM + k);
      acc[i] = fmaf(w.x, x.x, fmaf(w.y, x.y, fmaf(w.z, x.z, fmaf(w.w, x.w, acc[i]))));
    }
  }
#pragma unroll
  for (int i = 0; i < 16; ++i) {
    int row = tbc * 16 + i;
    if (n < 1536) P_ru[(size_t)row * 1536 + n] = acc[i];
    else          P_c[(size_t)row * 768 + (n - 1536)] = acc[i];
  }
}

// ---- persistent sequential kernel — ctx in LDS; pbuf/psum in XCD L2 ----
// block identity: physical (xcd, slot<32). attention batch bA = 2*xcd+(slot&1),
// chunk = slot>>1 (32 enc positions in LDS). gid = xcd*32+slot owns r rows
// gid*3.., u rows = c rows = gid*3.. (u never leaves registers).
// Per t: prefetch(t-valid loads) | A1 scores | A2a partials->L2 | lbar |
// A2b reduce->attnc(IF) | gbar | B (r->IF, u regs, c-attn partial) | gbar |
// C (c h-part + h update ->IF) | gbar.
__global__ void __launch_bounds__(512, 1) k_seq(
    const float* __restrict__ ctx, const float* __restrict__ mask,
    const float* __restrict__ Wr, const float* __restrict__ Wu,
    const float* __restrict__ Wc,
    const float* __restrict__ P_ru, const float* __restrict__ P_c,
    float* __restrict__ h_all, float* __restrict__ attnc,
    float* __restrict__ r_coh, float* __restrict__ pbuf,
    float* __restrict__ psum,
    unsigned* __restrict__ slotctr, unsigned* __restrict__ leaf,
    unsigned* __restrict__ root, unsigned* __restrict__ lbc) {
  extern __shared__ float dynpad[];
  float* ctx_lds = dynpad;              // [32][768] = 24576 floats (96 KB)
  float* e_lds   = dynpad + 24576;      // [32]
  float* pred    = dynpad + 24576 + 32; // [48][17] padded = 816
  float* psh     = dynpad + 24576 + 32 + 816;  // [16]
  __shared__ int slot_sh;
  __shared__ int done_sh;
  const int tid = threadIdx.x;
  const int lane = tid & 63;
  const int wv = tid >> 6;  // 0..7
  int xcd;
  asm volatile("s_getreg_b32 %0, hwreg(HW_REG_XCC_ID)" : "=s"(xcd));
  xcd &= 7;
  if (tid == 0) slot_sh = (int)afadd(&slotctr[xcd * 16]);
  __syncthreads();
  const int slot = slot_sh;            // 0..31 (1 block/CU guaranteed by LDS)
  const int gid = xcd * 32 + slot;     // 0..255 unique
  const int bA = 2 * xcd + (slot & 1); // attention batch
  const int chunk = slot >> 1;         // 0..15 (32 positions)
  const int dsl = chunk * 48;          // A2b dim-slice base
  const int rg0 = gid * 3;             // r rows 0..767
  const int cg0 = gid * 3;             // u & c rows 0..767
  const int b0 = 2 * wv;               // this wave's two batches (B/C)
  const int rl  = (lane + 2 * slot) & 63;  // rotated lane for gate cols
  const int rl1 = (lane + 4 * chunk) & 63; // rotated lane for A1 h/ctx cols
  volatile int* done = &done_sh;

  // ---- stage this block's ctx chunk (32 rows x 768) into LDS, ONCE ----
  {
    const float* chunkbase = ctx + ((size_t)(bA * ENC + chunk * 32)) * DIM;
#pragma unroll
    for (int k = 0; k < 12; ++k) {
      const int f = k * 2048 + tid * 4;
      *(float4*)(ctx_lds + f) = *(const float4*)(chunkbase + f);
    }
  }

  // ---- stage 9 W rows (3 Wr, 3 Wu, 3 Wc) into per-lane VGPRs (bf16 packed)
  // column mapping uses the SAME rotated lane rl as the B/C x-loads.
  unsigned int wreg[9][12];
#pragma unroll
  for (int i = 0; i < 9; ++i) {
    const float* src = (i < 3) ? (Wr + (size_t)(rg0 + i) * 2304)
                     : (i < 6) ? (Wu + (size_t)(cg0 + i - 3) * 2304)
                               : (Wc + (size_t)(cg0 + i - 6) * 2304);
#pragma unroll
    for (int j = 0; j < 6; ++j) {
      int xcol = 4 * rl + 256 * j;
      int scol = (j < 3) ? xcol : (1536 + xcol - 768);
      float4 v = *(const float4*)(src + scol);
      wreg[i][2 * j]     = (f2bf(v.x)) | (f2bf(v.y) << 16);
      wreg[i][2 * j + 1] = (f2bf(v.z)) | (f2bf(v.w) << 16);
    }
  }
  // attention mask-add for this wave's 4 positions
  float madd[4];
#pragma unroll
  for (int i = 0; i < 4; ++i)
    madd[i] = (1.0f - mask[bA * ENC + chunk * 32 + 4 * wv + i]) * NEGF;

  __syncthreads();  // ctx_lds ready for all waves

  int bidx = 0;
  for (int t = 0; t < Tn; ++t) {
    // ===== prefetch: every t-valid load, issued before the A-phase ========
    float4 xvh[2][3];  // h-part gate inputs for B (and C)
#pragma unroll
    for (int bb = 0; bb < 2; ++bb) {
      const float* hb = h_all + (size_t)(t * Bdim + b0 + bb) * DIM;
#pragma unroll
      for (int j = 0; j < 3; ++j)
        xvh[bb][j] = *(const float4*)(hb + 4 * rl + 256 * j);
    }
    float Pr3[3], Pu3[3], Pc3[3], hp3[3];
    if (lane < 2) {
      const int b = b0 + lane;
#pragma unroll
      for (int i = 0; i < 3; ++i) {
        Pr3[i] = P_ru[(size_t)(t * Bdim + b) * 1536 + rg0 + i];
        Pu3[i] = P_ru[(size_t)(t * Bdim + b) * 1536 + 768 + cg0 + i];
        Pc3[i] = P_c[(size_t)(t * Bdim + b) * DIM + cg0 + i];
        hp3[i] = h_all[(size_t)(t * Bdim + b) * DIM + cg0 + i];
      }
    }

    // ===== A1: scores for this chunk's 32 rows (4 per wave), from LDS ======
    {
      const float* hrow = h_all + (size_t)(t * Bdim + bA) * DIM;
      float hreg[12];
#pragma unroll
      for (int j = 0; j < 12; ++j) hreg[j] = hrow[rl1 + 64 * j];
#pragma unroll
      for (int i = 0; i < 4; ++i) {
        const int rr = 4 * wv + i;
        const float* crow = ctx_lds + rr * 768;
        float dot = 0.f;
#pragma unroll
        for (int j = 0; j < 12; ++j) dot = fmaf(crow[rl1 + 64 * j], hreg[j], dot);
        dot = wred_sum(dot);
        if (lane == 0) e_lds[rr] = __expf(fmaf(dot, SCALEF, madd[i]));
      }
    }
    __syncthreads();  // e_lds ready

    // ===== A2a: esum + 768-dim weighted partial -> XCD-local L2 ===========
    if (wv == 0) {
      float ev = (lane < 32) ? e_lds[lane] : 0.f;
      float es = wred_sum(ev);
      if (lane == 0) wstore(&psum[bA * 16 + chunk], es);
    }
    if (tid < 384) {
      const int d0 = 2 * tid;
      float a0 = 0.f, a1 = 0.f;
#pragma unroll 8
      for (int r = 0; r < 32; ++r) {
        const float e = e_lds[r];
        const float2 c2 = *(const float2*)(ctx_lds + r * 768 + d0);
        a0 = fmaf(e, c2.x, a0);
        a1 = fmaf(e, c2.y, a1);
      }
      wstore2(&pbuf[(size_t)(bA * 16 + chunk) * 768 + d0], a0, a1);
    }
    lbar(lbc, xcd, 32u * (unsigned)(t + 1), done);

    // ===== A2b: L2 reads, reduce 16 partials -> normalized attnc (IF) =====
    {
      const int ch = tid >> 5, d2 = tid & 31;  // 16 chunks x 32 sub-slots
      if (d2 < 24) {  // 24 float2 = this batch's 48-dim slice
        float2 v = l2ldf2(&pbuf[(size_t)(bA * 16 + ch) * 768 + dsl + 2 * d2]);
        pred[(2 * d2) * 17 + ch] = v.x;
        pred[(2 * d2 + 1) * 17 + ch] = v.y;
      } else if (d2 == 24) {
        psh[ch] = l2ldf(&psum[bA * 16 + ch]);
      }
      __syncthreads();
      if (tid < 48) {
        float s = 0.f, den = 0.f;
#pragma unroll
        for (int p = 0; p < 16; ++p) { s += pred[tid * 17 + p]; den += psh[p]; }
        astore(&attnc[(size_t)(t * Bdim + bA) * DIM + dsl + tid], s / den);
      }
    }
    gbar(leaf, root, bidx++, xcd, done);

    // ===== B: r (IF store) + u (regs) + c-attn partial =====================
    float4 xv[2][3];
#pragma unroll
    for (int bb = 0; bb < 2; ++bb) {
      const float* ab = attnc + (size_t)(t * Bdim + b0 + bb) * DIM;
#pragma unroll
      for (int j = 0; j < 3; ++j)
        xv[bb][j] = *(const float4*)(ab + 4 * rl + 256 * j);
    }
    float u_reg[3], ca0[3], ca1[3];
#pragma unroll
    for (int i = 0; i < 3; ++i) {  // r rows rg0..rg0+2
      float d0 = 0.f, d1 = 0.f;
#pragma unroll
      for (int j = 0; j < 6; ++j) {
        const unsigned int p0 = wreg[i][2 * j], p1 = wreg[i][2 * j + 1];
        const float w0 = bflo(p0), w1 = bfhi(p0), w2 = bflo(p1), w3 = bfhi(p1);
        const float4 x0 = (j < 3) ? xv[0][j] : xvh[0][j - 3];
        const float4 x1 = (j < 3) ? xv[1][j] : xvh[1][j - 3];
        d0 = fmaf(w0, x0.x, fmaf(w1, x0.y, fmaf(w2, x0.z, fmaf(w3, x0.w, d0))));
        d1 = fmaf(w0, x1.x, fmaf(w1, x1.y, fmaf(w2, x1.z, fmaf(w3, x1.w, d1))));
      }
      d0 = wred_sum(d0);
      d1 = wred_sum(d1);
      if (lane < 2) {
        const float s = sigmf(Pr3[i] + (lane ? d1 : d0));
        astore(&r_coh[(size_t)(t * Bdim + b0 + lane) * DIM + rg0 + i], s);
      }
    }
#pragma unroll
    for (int i = 0; i < 3; ++i) {  // u rows + c-gate attn-part partials
      float d0 = 0.f, d1 = 0.f, c0 = 0.f, c1 = 0.f;
#pragma unroll
      for (int j = 0; j < 6; ++j) {
        const unsigned int p0 = wreg[3 + i][2 * j], p1 = wreg[3 + i][2 * j + 1];
        const float w0 = bflo(p0), w1 = bfhi(p0), w2 = bflo(p1), w3 = bfhi(p1);
        const float4 x0 = (j < 3) ? xv[0][j] : xvh[0][j - 3];
        const float4 x1 = (j < 3) ? xv[1][j] : xvh[1][j - 3];
        d0 = fmaf(w0, x0.x, fmaf(w1, x0.y, fmaf(w2, x0.z, fmaf(w3, x0.w, d0))));
        d1 = fmaf(w0, x1.x, fmaf(w1, x1.y, fmaf(w2, x1.z, fmaf(w3, x1.w, d1))));
      }
#pragma unroll
      for (int j = 0; j < 3; ++j) {  // c attn part (cols j=0..2)
        const unsigned int p0 = wreg[6 + i][2 * j], p1 = wreg[6 + i][2 * j + 1];
        const float w0 = bflo(p0), w1 = bfhi(p0), w2 = bflo(p1), w3 = bfhi(p1);
        c0 = fmaf(w0, xv[0][j].x, fmaf(w1, xv[0][j].y, fmaf(w2, xv[0][j].z, fmaf(w3, xv[0][j].w, c0))));
        c1 = fmaf(w0, xv[1][j].x, fmaf(w1, xv[1][j].y, fmaf(w2, xv[1][j].z, fmaf(w3, xv[1][j].w, c1))));
      }
      d0 = wred_sum(d0);
      d1 = wred_sum(d1);
      if (lane < 2) u_reg[i] = sigmf(Pu3[i] + (lane ? d1 : d0));
      ca0[i] = c0;  // per-lane partials, reduced in C
      ca1[i] = c1;
    }
    gbar(leaf, root, bidx++, xcd, done);

    // ===== C: c-gate h-part + h update (u, hp, Pc from registers) ==========
    float4 vh[2][3];
#pragma unroll
    for (int bb = 0; bb < 2; ++bb) {
      const float* rb = r_coh + (size_t)(t * Bdim + b0 + bb) * DIM;
#pragma unroll
      for (int j = 0; j < 3; ++j) {
        float4 rv = *(const float4*)(rb + 4 * rl + 256 * j);  // fresh t-line
        vh[bb][j] = make_float4(xvh[bb][j].x * rv.x, xvh[bb][j].y * rv.y,
                                xvh[bb][j].z * rv.z, xvh[bb][j].w * rv.w);
      }
    }
#pragma unroll
    for (int i = 0; i < 3; ++i) {
      float d0 = ca0[i], d1 = ca1[i];
#pragma unroll
      for (int j = 0; j < 3; ++j) {
        const unsigned int p0 = wreg[6 + i][2 * (3 + j)], p1 = wreg[6 + i][2 * (3 + j) + 1];
        const float w0 = bflo(p0), w1 = bfhi(p0), w2 = bflo(p1), w3 = bfhi(p1);
        d0 = fmaf(w0, vh[0][j].x, fmaf(w1, vh[0][j].y, fmaf(w2, vh[0][j].z, fmaf(w3, vh[0][j].w, d0))));
        d1 = fmaf(w0, vh[1][j].x, fmaf(w1, vh[1][j].y, fmaf(w2, vh[1][j].z, fmaf(w3, vh[1][j].w, d1))));
      }
      d0 = wred_sum(d0);
      d1 = wred_sum(d1);
      if (lane < 2) {
        const float c = tanhf(Pc3[i] + (lane ? d1 : d0));
        astore(&h_all[(size_t)((t + 1) * Bdim + b0 + lane) * DIM + cg0 + i],
               hp3[i] + u_reg[i] * (c - hp3[i]));
      }
    }
    gbar(leaf, root, bidx++, xcd, done);
  }
}

// ---- deferred: out_all & copyq for all 1024 rows ----
__global__ void __launch_bounds__(256, 2) k_out(
    const float* __restrict__ Wo, const float* __restrict__ bo,
    const float* __restrict__ Wcp, const float* __restrict__ bcp,
    const float* __restrict__ h_all, float* __restrict__ out_all,
    float* __restrict__ copyq) {
  const int nb = blockIdx.x, tbc = blockIdx.y;
  const int n = nb * 256 + threadIdx.x;  // 0..1535
  const float* wrow;
  float bias;
  if (n < 768) { wrow = Wo + (size_t)n * 768;          bias = bo[n]; }
  else         { wrow = Wcp + (size_t)(n - 768) * 768; bias = bcp[n - 768]; }
  const float* hbase = h_all + (size_t)(tbc * 16 + 16) * DIM;  // h_new = slot t+1
  float acc[16];
#pragma unroll
  for (int i = 0; i < 16; ++i) acc[i] = bias;
  for (int k = 0; k < DIM; k += 4) {
    float4 w = *(const float4*)(wrow + k);
#pragma unroll
    for (int i = 0; i < 16; ++i) {
      float4 x = *(const float4*)(hbase + i * DIM + k);
      acc[i] = fmaf(w.x, x.x, fmaf(w.y, x.y, fmaf(w.z, x.z, fmaf(w.w, x.w, acc[i]))));
    }
  }
#pragma unroll
  for (int i = 0; i < 16; ++i) {
    int row = tbc * 16 + i;
    if (n < 768) out_all[(size_t)row * 768 + n] = acc[i];
    else         copyq[(size_t)row * 768 + (n - 768)] = acc[i];
  }
}

// ---- deferred: copy softmax num/den per (t,b) ----
__global__ void __launch_bounds__(512, 2) k_copy(
    const int* __restrict__ ids, const int* __restrict__ dtg,
    const float* __restrict__ ctx, const float* __restrict__ mask,
    const float* __restrict__ copyq,
    float* __restrict__ cnum, float* __restrict__ cden) {
  const int sc = blockIdx.x, b = blockIdx.y;
  const int lane = threadIdx.x & 63;
  const int seg = __builtin_amdgcn_readfirstlane(threadIdx.x >> 6);
  const int s = sc * 64 + lane;
  __shared__ float part[8][64];
  float creg[96];
  const float* crow = ctx + ((size_t)(b * ENC + s)) * DIM + seg * 96;
#pragma unroll
  for (int kk = 0; kk < 96; kk += 4) {
    float4 v = *(const float4*)(crow + kk);
    creg[kk] = v.x; creg[kk + 1] = v.y; creg[kk + 2] = v.z; creg[kk + 3] = v.w;
  }
  const float madd = (1.0f - mask[b * ENC + s]) * NEGF;
  const int myid = ids[b * ENC + s];
  for (int t = 0; t < Tn; ++t) {
    const int row = t * Bdim + b;
    const float* q = copyq + (size_t)row * 768 + seg * 96;
    float dot = 0.f;
#pragma unroll
    for (int kk = 0; kk < 96; kk += 4) {
      float4 qv = *(const float4*)(q + kk);
      dot = fmaf(qv.x, creg[kk], fmaf(qv.y, creg[kk + 1],
            fmaf(qv.z, creg[kk + 2], fmaf(qv.w, creg[kk + 3], dot))));
    }
    part[seg][lane] = dot;
    __syncthreads();
    if (threadIdx.x < 64) {
      float logit = madd;
#pragma unroll
      for (int w = 0; w < 8; ++w) logit += part[w][lane];
      float e = __expf(logit);
      int tgt = dtg[b * Tn + t];
      float ne = (myid == tgt) ? e : 0.f;
      float dsum = wred_sum(e);
      float nsum = wred_sum(ne);
      if (lane == 0) {
        atomicAdd(&cden[row], dsum);
        if (nsum != 0.f) atomicAdd(&cnum[row], nsum);
      }
    }
    __syncthreads();
  }
}

// ---- deferred: vocab exp-sum per row. grid (83, 32) x 256, 32 rows/block ----
__global__ void __launch_bounds__(256, 1) k_vocab(
    const float* __restrict__ emb, const float* __restrict__ out_all,
    float* __restrict__ S) {
  const int vc = blockIdx.x, tbc = blockIdx.y;
  const int tb0 = tbc * 32;
  const int v = vc * 256 + threadIdx.x;
  const bool valid = v < VOCAB;
  const int vv = valid ? v : 0;
  float acc[32];
#pragma unroll
  for (int i = 0; i < 32; ++i) acc[i] = 0.f;
  const float* erow = emb + (size_t)vv * DIM;
  for (int k = 0; k < DIM; k += 4) {
    float4 w = *(const float4*)(erow + k);
#pragma unroll
    for (int i = 0; i < 32; ++i) {
      float4 a = *(const float4*)(out_all + (size_t)(tb0 + i) * DIM + k);
      acc[i] = fmaf(w.x, a.x, fmaf(w.y, a.y, fmaf(w.z, a.z, fmaf(w.w, a.w, acc[i]))));
    }
  }
  __shared__ float rowsum[32];
  if (threadIdx.x < 32) rowsum[threadIdx.x] = 0.f;
  __syncthreads();
  const int lane = threadIdx.x & 63;
#pragma unroll
  for (int i = 0; i < 32; ++i) {
    float e = valid ? __expf(acc[i]) : 0.f;
    float r = wred_sum(e);
    if (lane == 0) atomicAdd(&rowsum[i], r);
  }
  __syncthreads();
  if (threadIdx.x < 32) atomicAdd(&S[tb0 + threadIdx.x], rowsum[threadIdx.x]);
}

// ---- deferred: per-row target prob + loss accumulation ----
__global__ void k_tgt(
    const int* __restrict__ dtg, const float* __restrict__ out_all,
    const float* __restrict__ emb, const float* __restrict__ Wm,
    const float* __restrict__ bm, const float* __restrict__ h_all,
    const float* __restrict__ S, const float* __restrict__ cnum,
    const float* __restrict__ cden, float* __restrict__ loss) {
  const int lane = threadIdx.x & 63;
  const int w = __builtin_amdgcn_readfirstlane(threadIdx.x >> 6);
  for (int rr = 0; rr < 16; ++rr) {
    const int row = (blockIdx.x * 4 + w) * 16 + rr;
    const int t = row >> 4, b = row & 15;
    const int tgt = dtg[b * Tn + t];
    const float* orow = out_all + (size_t)row * DIM + lane * 12;
    const float* erow = emb + (size_t)tgt * DIM + lane * 12;
    const float* hrow = h_all + (size_t)(row + 16) * DIM + lane * 12;
    const float* wm = Wm + lane * 12;
    float lt = 0.f, md = 0.f;
#pragma unroll
    for (int k = 0; k < 12; k += 4) {
      float4 o = *(const float4*)(orow + k);
      float4 e = *(const float4*)(erow + k);
      float4 h = *(const float4*)(hrow + k);
      float4 m = *(const float4*)(wm + k);
      lt = fmaf(o.x, e.x, fmaf(o.y, e.y, fmaf(o.z, e.z, fmaf(o.w, e.w, lt))));
      md = fmaf(m.x, h.x, fmaf(m.y, h.y, fmaf(m.z, h.z, fmaf(m.w, h.w, md))));
    }
    lt = wred_sum(lt);
    md = wred_sum(md);
    if (lane == 0 && tgt != 0) {
      float mode = sigmf(md + bm[0]);
      float pv = __expf(lt) / S[row] * mode;
      float den = cden[row];
      float pc = (den > 0.f) ? (cnum[row] / den) : 0.f;
      float p = pv + (1.0f - mode) * pc;
      atomicAdd(&loss[0], -logf(p + 1e-6f));
      atomicAdd(&loss[1], 1.0f);
    }
  }
}

__global__ void k_write(const float* __restrict__ loss, float* __restrict__ out) {
  if (threadIdx.x < Bdim) out[threadIdx.x] = loss[0] / loss[1];
}

extern "C" void kernel_launch(void* const* d_in, const int* in_sizes, int n_in,
                              void* d_out, int out_size, void* d_ws, size_t ws_size,
                              hipStream_t stream) {
  (void)in_sizes; (void)n_in; (void)out_size; (void)ws_size;
  const int*   input_ids = (const int*)d_in[0];
  const float* ctx       = (const float*)d_in[1];
  const float* cmask     = (const float*)d_in[2];
  const int*   din       = (const int*)d_in[3];
  const int*   dtg       = (const int*)d_in[4];
  const float* embW      = (const float*)d_in[7];
  const float* Wr = (const float*)d_in[8];  const float* br  = (const float*)d_in[9];
  const float* Wu = (const float*)d_in[10]; const float* bu  = (const float*)d_in[11];
  const float* Wc = (const float*)d_in[12]; const float* bc  = (const float*)d_in[13];
  const float* Wo = (const float*)d_in[14]; const float* bo  = (const float*)d_in[15];
  const float* Wcp= (const float*)d_in[16]; const float* bcp = (const float*)d_in[17];
  const float* Wm = (const float*)d_in[18]; const float* bm  = (const float*)d_in[19];
  const float* ih = (const float*)d_in[20];

  float* ws      = (float*)d_ws;
  float* P_ru    = ws;                          // 1024*1536
  float* P_c     = P_ru + 1024 * 1536;          // 1024*768
  float* h_all   = P_c + 1024 * 768;            // 65*16*768
  float* out_all = h_all + 65 * 16 * 768;       // 1024*768
  float* copyq   = out_all + 1024 * 768;        // 1024*768
  float* attnc   = copyq + 1024 * 768;          // 64*16*768 (normalized attn)
  float* r_coh   = attnc + 64 * 16 * 768;       // 64*16*768 (per-t fresh lines)
  float* pbuf    = r_coh + 64 * 16 * 768;       // 16*16*768 (XCD-L2-local)
  float* psum    = pbuf + 16 * 16 * 768;        // 256      (XCD-L2-local)
  // ---- coherently-zeroed region ----
  float* S       = psum + 256;                  // 1024
  float* cnum    = S + 1024;                    // 1024
  float* cden    = cnum + 1024;                 // 1024
  float* loss    = cden + 1024;                 // 2 (+30 pad -> 128B alignment)
  unsigned* slotctr = (unsigned*)(loss + 32);   // 8*16
  unsigned* leaf    = slotctr + 8 * 16;         // 192*8*16
  unsigned* root    = leaf + 192 * 8 * 16;      // 192*16
  unsigned* lbc     = root + 192 * 16;          // 8*16
  const int nzero64 = (3 * 1024 + 32 + 8 * 16 + 192 * 8 * 16 + 192 * 16 + 8 * 16) / 2;

  hipFuncSetAttribute((const void*)k_seq,
                      hipFuncAttributeMaxDynamicSharedMemorySize, DYN_LDS);

  k_zero_coh<<<64, 1024, 0, stream>>>((unsigned long long*)S, nzero64);
  k_h0<<<12, 1024, 0, stream>>>(ih, h_all);
  k_pre<<<dim3(9, 64), 256, 0, stream>>>(din, embW, Wr, br, Wu, bu, Wc, bc, P_ru, P_c);

  k_seq<<<NBLK, 512, DYN_LDS, stream>>>(ctx, cmask, Wr, Wu, Wc, P_ru, P_c,
                                        h_all, attnc, r_coh, pbuf, psum,
                                        slotctr, leaf, root, lbc);

  k_out<<<dim3(6, 64), 256, 0, stream>>>(Wo, bo, Wcp, bcp, h_all, out_all, copyq);
  k_copy<<<dim3(8, 16), 512, 0, stream>>>(input_ids, dtg, ctx, cmask, copyq, cnum, cden);
  k_vocab<<<dim3(83, 32), 256, 0, stream>>>(embW, out_all, S);
  k_tgt<<<16, 256, 0, stream>>>(dtg, out_all, embW, Wm, bm, h_all, S, cnum, cden, loss);
  k_write<<<1, 64, 0, stream>>>(loss, (float*)d_out);
}